// Round 6
// baseline (66.963 us; speedup 1.0000x reference)
//
#include <hip/hip_runtime.h>

// Problem constants (match reference)
#define D_DIM 160
#define H_DIM 192
#define W_DIM 224
#define BLOCK 256
#define S_ITERS 2   // super-iterations per block; block covers 2048 voxels

typedef float f32x4 __attribute__((ext_vector_type(4)));  // native vec: nontemporal-ok

// out[b,d,h,w,i] = sum_j (A[b,i,j] - delta_ij) * mesh_j + t[b,i]
// mesh = (d - 79.5, h - 95.5, w - 111.5)
//
// Round-4 structure (best so far, 59.5us): per super-iteration a block covers
// 1024 consecutive voxels; each thread computes 4 consecutive voxels (4 | 224,
// never crosses a row), writes 12 floats to LDS, block drains 768 float4
// unit-stride, fully coalesced.
// Round-5 change: drain stores are NONTEMPORAL (nt flag) — pure streaming
// write should not allocate in L2/L3 (330MB > 256MB L3; write-allocate adds
// eviction backpressure in the kernel tail).
__global__ __launch_bounds__(BLOCK) void AffineToDenseShift_kernel(
    const float* __restrict__ matrix, float* __restrict__ out) {
  __shared__ alignas(16) float lds[3 * 1024];  // 12,288 B

  const int b = blockIdx.y;
  const float* M = matrix + b * 12;  // wave-uniform -> scalar loads

  const float a00 = M[0] - 1.0f, a01 = M[1],        a02 = M[2],         t0 = M[3];
  const float a10 = M[4],        a11 = M[5] - 1.0f, a12 = M[6],         t1 = M[7];
  const float a20 = M[8],        a21 = M[9],        a22 = M[10] - 1.0f, t2 = M[11];

  const long long batch_floats = (long long)D_DIM * H_DIM * W_DIM * 3;
  f32x4* __restrict__ dst4 = (f32x4*)(out + (long long)b * batch_floats);

  const unsigned t = threadIdx.x;
  const unsigned vbase0 = blockIdx.x * (1024u * S_ITERS) + 4u * t;
  const unsigned f4base0 = blockIdx.x * (768u * S_ITERS) + t;

  f32x4* const Lw = (f32x4*)&lds[12u * t];

  #pragma unroll
  for (int s = 0; s < S_ITERS; ++s) {
    const unsigned v = vbase0 + (unsigned)s * 1024u;  // first of 4 consecutive voxels

    const unsigned w = v % (unsigned)W_DIM;           // magic-mul div chain
    const unsigned r = v / (unsigned)W_DIM;
    const unsigned h = r % (unsigned)H_DIM;
    const unsigned d = r / (unsigned)H_DIM;

    const float md = (float)d - (float)(D_DIM - 1) * 0.5f;
    const float mh = (float)h - (float)(H_DIM - 1) * 0.5f;
    const float mw = (float)w - (float)(W_DIM - 1) * 0.5f;

    const float x0 = fmaf(a00, md, fmaf(a01, mh, fmaf(a02, mw, t0)));
    const float y0 = fmaf(a10, md, fmaf(a11, mh, fmaf(a12, mw, t1)));
    const float z0 = fmaf(a20, md, fmaf(a21, mh, fmaf(a22, mw, t2)));
    // 3 more voxels along w (same row guaranteed): += column-2 of (A - I)
    const float x1 = x0 + a02, y1 = y0 + a12, z1 = z0 + a22;
    const float x2 = x1 + a02, y2 = y1 + a12, z2 = z1 + a22;
    const float x3 = x2 + a02, y3 = y2 + a12, z3 = z2 + a22;

    Lw[0] = (f32x4){x0, y0, z0, x1};
    Lw[1] = (f32x4){y1, z1, x2, y2};
    Lw[2] = (f32x4){z2, x3, y3, z3};
    __syncthreads();

    // Coalesced drain: 768 float4 = 3 per thread, unit-stride across the
    // block, nontemporal (streaming) stores.
    const f32x4* const Ls = (const f32x4*)lds;
    f32x4* const dc = dst4 + (f4base0 + (unsigned)s * 768u - t);  // block chunk base
    __builtin_nontemporal_store(Ls[t],        &dc[t]);
    __builtin_nontemporal_store(Ls[t + 256u], &dc[t + 256u]);
    __builtin_nontemporal_store(Ls[t + 512u], &dc[t + 512u]);
    __syncthreads();  // protect LDS overwrite next super-iter
  }
}

extern "C" void kernel_launch(void* const* d_in, const int* in_sizes, int n_in,
                              void* d_out, int out_size, void* d_ws, size_t ws_size,
                              hipStream_t stream) {
  const float* matrix = (const float*)d_in[0];
  float* out = (float*)d_out;

  const int batch = in_sizes[0] / 12;  // [B,3,4] fp32
  const long long per_batch_vox = (long long)D_DIM * H_DIM * W_DIM;       // 6,881,280
  const int blocks_x = (int)(per_batch_vox / (1024LL * S_ITERS));         // 3360, exact

  dim3 grid(blocks_x, batch);
  AffineToDenseShift_kernel<<<grid, BLOCK, 0, stream>>>(matrix, out);
}

// Round 7
// 59.697 us; speedup vs baseline: 1.1217x; 1.1217x over previous
//
#include <hip/hip_runtime.h>

// Problem constants (match reference)
#define D_DIM 160
#define H_DIM 192
#define W_DIM 224
#define BLOCK 512   // one pass: block covers 2048 consecutive voxels, 1 barrier

typedef float f32x4 __attribute__((ext_vector_type(4)));

// out[b,d,h,w,i] = sum_j (A[b,i,j] - delta_ij) * mesh_j + t[b,i]
// mesh = (d - 79.5, h - 95.5, w - 111.5)
//
// Round-4 structure (best, 59.5us) with the loop flattened: each thread
// computes 4 CONSECUTIVE voxels (4 | 224 -> never crosses a row: one
// %224/%192 magic-div chain, 9 fma, 9 adds), writes 12 floats to LDS;
// ONE barrier; block drains 1536 float4 unit-stride (64 lanes x 16B
// contiguous per store). nt reverted (round 6: bypassing L2 write
// aggregation cost +12%). No loop, no trailing sync.
__global__ __launch_bounds__(BLOCK) void AffineToDenseShift_kernel(
    const float* __restrict__ matrix, float* __restrict__ out) {
  __shared__ alignas(16) float lds[3 * 2048];  // 24,576 B

  const int b = blockIdx.y;
  const float* M = matrix + b * 12;  // wave-uniform -> scalar loads

  const float a00 = M[0] - 1.0f, a01 = M[1],        a02 = M[2],         t0 = M[3];
  const float a10 = M[4],        a11 = M[5] - 1.0f, a12 = M[6],         t1 = M[7];
  const float a20 = M[8],        a21 = M[9],        a22 = M[10] - 1.0f, t2 = M[11];

  const long long batch_floats = (long long)D_DIM * H_DIM * W_DIM * 3;
  f32x4* __restrict__ dst4 = (f32x4*)(out + (long long)b * batch_floats);

  const unsigned t = threadIdx.x;
  const unsigned v = blockIdx.x * 2048u + 4u * t;  // first of 4 consecutive voxels

  const unsigned w = v % (unsigned)W_DIM;          // magic-mul div chain
  const unsigned r = v / (unsigned)W_DIM;
  const unsigned h = r % (unsigned)H_DIM;
  const unsigned d = r / (unsigned)H_DIM;

  const float md = (float)d - (float)(D_DIM - 1) * 0.5f;
  const float mh = (float)h - (float)(H_DIM - 1) * 0.5f;
  const float mw = (float)w - (float)(W_DIM - 1) * 0.5f;

  const float x0 = fmaf(a00, md, fmaf(a01, mh, fmaf(a02, mw, t0)));
  const float y0 = fmaf(a10, md, fmaf(a11, mh, fmaf(a12, mw, t1)));
  const float z0 = fmaf(a20, md, fmaf(a21, mh, fmaf(a22, mw, t2)));
  // 3 more voxels along w (same row guaranteed): += column-2 of (A - I)
  const float x1 = x0 + a02, y1 = y0 + a12, z1 = z0 + a22;
  const float x2 = x1 + a02, y2 = y1 + a12, z2 = z1 + a22;
  const float x3 = x2 + a02, y3 = y2 + a12, z3 = z2 + a22;

  f32x4* const Lw = (f32x4*)&lds[12u * t];
  Lw[0] = (f32x4){x0, y0, z0, x1};
  Lw[1] = (f32x4){y1, z1, x2, y2};
  Lw[2] = (f32x4){z2, x3, y3, z3};
  __syncthreads();

  // Coalesced drain: 1536 float4 = 3 per thread, unit-stride across the block.
  const f32x4* const Ls = (const f32x4*)lds;
  f32x4* const dc = dst4 + (unsigned)blockIdx.x * 1536u;
  dc[t]         = Ls[t];
  dc[t + 512u]  = Ls[t + 512u];
  dc[t + 1024u] = Ls[t + 1024u];
}

extern "C" void kernel_launch(void* const* d_in, const int* in_sizes, int n_in,
                              void* d_out, int out_size, void* d_ws, size_t ws_size,
                              hipStream_t stream) {
  const float* matrix = (const float*)d_in[0];
  float* out = (float*)d_out;

  const int batch = in_sizes[0] / 12;  // [B,3,4] fp32
  const long long per_batch_vox = (long long)D_DIM * H_DIM * W_DIM;  // 6,881,280
  const int blocks_x = (int)(per_batch_vox / 2048LL);                // 3360, exact

  dim3 grid(blocks_x, batch);
  AffineToDenseShift_kernel<<<grid, BLOCK, 0, stream>>>(matrix, out);
}